// Round 4
// baseline (298.833 us; speedup 1.0000x reference)
//
#include <hip/hip_runtime.h>

// Problem constants (z: [16,256,64,64] f32, embedding: [1024,256] f32)
#define NN 65536   // B*H*W rows
#define KK 1024
// flag if fixed-point top-2 gap < 2098 (= 4e-3 * 2^19): ~10 sigma of 1-pass bf16 noise
#define TFLAG_FIX 2098u

typedef __bf16 bf16x8 __attribute__((ext_vector_type(8)));
typedef float f32x16 __attribute__((ext_vector_type(16)));

__device__ __forceinline__ unsigned short f2bf(float x){
  unsigned u = __float_as_uint(x);
  u += 0x7FFFu + ((u >> 16) & 1u);
  return (unsigned short)(u >> 16);
}
__device__ __forceinline__ float bf2f(unsigned short h){
  return __uint_as_float(((unsigned)h) << 16);
}
__device__ __forceinline__ void dma16(const uint4* g, uint4* l){
  __builtin_amdgcn_global_load_lds(
      (const __attribute__((address_space(1))) void*)g,
      (__attribute__((address_space(3))) void*)l, 16, 0, 0);
}
__device__ __forceinline__ unsigned long long shfl_xor_u64(unsigned long long v, int m){
  unsigned lo = (unsigned)__shfl_xor((int)(unsigned)v, m, 64);
  unsigned hi = (unsigned)__shfl_xor((int)(unsigned)(v >> 32), m, 64);
  return ((unsigned long long)hi << 32) | lo;
}
union U4S8 { uint4 v; unsigned short u[8]; };

// Fragment-major layout for bf16 matrices [rows][256 c]:
// uint4 (8 c-elems) for (row n, chunk q=c>>3) at index (n>>5)*1024 + q*32 + (n&31).

// ---------------- K0: normalize codebook. wnT is stored TRANSPOSED [c][k] (f32)
// so kern_rescue's per-channel codebook read is wave-coalesced (lane t reads
// wnT[c][2t..2t+1] -> contiguous span per wave instead of 64 scattered lines).
__global__ __launch_bounds__(64) void kern_prep(const float* __restrict__ emb,
    float* __restrict__ wnT, uint4* __restrict__ wnh4,
    float* __restrict__ wnn, float* __restrict__ wnn4)
{
  const int k = blockIdx.x, t = threadIdx.x;
  float4 v = ((const float4*)emb)[k*64 + t];
  float ss = fmaf(v.x, v.x, fmaf(v.y, v.y, fmaf(v.z, v.z, v.w * v.w)));
  #pragma unroll
  for (int m = 32; m > 0; m >>= 1) ss += __shfl_xor(ss, m, 64);
  float d = fmaxf(sqrtf(ss), 1e-12f);
  float w0 = v.x / d, w1 = v.y / d, w2 = v.z / d, w3 = v.w / d;
  // transposed store: wnT[c][k], c = 4t..4t+3 (one-time scattered 1MB write)
  wnT[(size_t)(4*t+0)*1024 + k] = w0;
  wnT[(size_t)(4*t+1)*1024 + k] = w1;
  wnT[(size_t)(4*t+2)*1024 + k] = w2;
  wnT[(size_t)(4*t+3)*1024 + k] = w3;
  unsigned short* base = (unsigned short*)wnh4;
  size_t o = ((size_t)(k >> 5) * 1024 + (size_t)(t >> 1) * 32 + (k & 31)) * 8 + (t & 1) * 4;
  base[o+0] = f2bf(w0); base[o+1] = f2bf(w1); base[o+2] = f2bf(w2); base[o+3] = f2bf(w3);
  float s2 = fmaf(w0, w0, fmaf(w1, w1, fmaf(w2, w2, w3 * w3)));
  #pragma unroll
  for (int m = 32; m > 0; m >>= 1) s2 += __shfl_xor(s2, m, 64);
  if (t == 0){ wnn[k] = s2; wnn4[k] = 4.0f - s2; }
}

// ---------------- K1: L2-normalize z along W, transpose to [N,C], split bf16 hi/lo,
// store BOTH in fragment-major layout. grid: (b*64+h)*4 + c-tile; block 256.
__global__ __launch_bounds__(256) void kern_znorm(const float* __restrict__ z,
    uint4* __restrict__ zfh4, uint4* __restrict__ zfl4)
{
  __shared__ float tile[64][65];  // [c_local][w]
  __shared__ float sinv[64];
  const int t = threadIdx.x;
  const int ct = blockIdx.x & 3;
  const int bh = blockIdx.x >> 2;     // b*64 + h
  const int c0 = ct * 64, q0 = ct * 8;
  const int cl = t >> 2, q = t & 3;
  const float4* zr = (const float4*)(z + ((size_t)(bh >> 6) * 256 + c0 + cl) * 4096
                                       + (size_t)(bh & 63) * 64);
  #pragma unroll
  for (int i = 0; i < 4; i++){
    float4 v = zr[q + 4*i];
    int w = (q + 4*i) * 4;
    tile[cl][w] = v.x; tile[cl][w+1] = v.y; tile[cl][w+2] = v.z; tile[cl][w+3] = v.w;
  }
  __syncthreads();
  if (t < 64){
    float ss = 0.f;
    #pragma unroll
    for (int w = 0; w < 64; w++){ float x = tile[t][w]; ss = fmaf(x, x, ss); }
    sinv[t] = 1.0f / fmaxf(sqrtf(ss), 1e-12f);
  }
  __syncthreads();
  #pragma unroll
  for (int j = 0; j < 2; j++){
    int p = t + 256 * j;
    int tI = p >> 8, rem = p & 255;
    int qq = rem >> 5, colI = rem & 31;
    int w = tI * 32 + colI;
    U4S8 hh, ll;
    #pragma unroll
    for (int e = 0; e < 8; e++){
      int c = qq * 8 + e;
      float v = tile[c][w] * sinv[c];
      hh.u[e] = f2bf(v);
      ll.u[e] = f2bf(v - bf2f(hh.u[e]));
    }
    size_t o = (size_t)(bh * 2 + tI) * 1024 + (size_t)(q0 + qq) * 32 + colI;
    zfh4[o] = hh.v;
    zfl4[o] = ll.v;
  }
}

// ---------------- K2: 1-pass bf16 MFMA GEMM, 64 rows x 32 codes per wave,
// code-split-2, DMA-staged double-buffered B, fixed-point packed-key top-2 per row.
__global__ __launch_bounds__(256, 2) void kern_gemm(
    const uint4* __restrict__ zA, const uint4* __restrict__ wB,
    const float* __restrict__ wnn4, uint2* __restrict__ pairs)
{
  __shared__ uint4 sB[2][1024];
  const int t = threadIdx.x;
  const int wv = t >> 6;
  const int lane = t & 63;
  const int col = lane & 31;
  const int half = lane >> 5;
  const int hb = blockIdx.x & 1;
  const int cb = hb * 512;
  const int rowBase = (blockIdx.x >> 1) * 256 + wv * 64;
  const int T0 = rowBase >> 5;

  bf16x8 a0[16], a1[16];
  {
    const uint4* r0 = zA + (size_t)T0 * 1024;
    const uint4* r1 = zA + (size_t)(T0 + 1) * 1024;
    const uint4* g0 = wB + (size_t)(cb >> 5) * 1024;
    dma16(g0 + (wv*4+0)*64 + lane, &sB[0][(wv*4+0)*64 + lane]);
    dma16(g0 + (wv*4+1)*64 + lane, &sB[0][(wv*4+1)*64 + lane]);
    dma16(g0 + (wv*4+2)*64 + lane, &sB[0][(wv*4+2)*64 + lane]);
    dma16(g0 + (wv*4+3)*64 + lane, &sB[0][(wv*4+3)*64 + lane]);
    #pragma unroll
    for (int s = 0; s < 16; s++){
      a0[s] = __builtin_bit_cast(bf16x8, r0[(2*s + half)*32 + col]);
      a1[s] = __builtin_bit_cast(bf16x8, r1[(2*s + half)*32 + col]);
    }
  }
  unsigned b1k[2][16], b2k[2][16];
  #pragma unroll
  for (int r = 0; r < 16; r++){
    b1k[0][r] = 0u; b1k[1][r] = 0u; b2k[0][r] = 0u; b2k[1][r] = 0u;
  }
  const int kinvBase = 1023 - cb - col;
  __syncthreads();

  for (int kt = 0; kt < 16; kt++){
    if (kt < 15){
      const uint4* gn = wB + (size_t)((cb >> 5) + kt + 1) * 1024;
      uint4* ld = &sB[(kt + 1) & 1][0];
      dma16(gn + (wv*4+0)*64 + lane, ld + (wv*4+0)*64 + lane);
      dma16(gn + (wv*4+1)*64 + lane, ld + (wv*4+1)*64 + lane);
      dma16(gn + (wv*4+2)*64 + lane, ld + (wv*4+2)*64 + lane);
      dma16(gn + (wv*4+3)*64 + lane, ld + (wv*4+3)*64 + lane);
    }
    const float c4k = wnn4[cb + kt*32 + col];
    const uint4* bp = &sB[kt & 1][half * 32 + col];
    f32x16 acc0, acc1;
    #pragma unroll
    for (int i = 0; i < 16; i++){ acc0[i] = 0.0f; acc1[i] = 0.0f; }
    #pragma unroll
    for (int s = 0; s < 16; s++){
      bf16x8 bs = __builtin_bit_cast(bf16x8, bp[s * 64]);
      acc0 = __builtin_amdgcn_mfma_f32_32x32x16_bf16(a0[s], bs, acc0, 0, 0, 0);
      acc1 = __builtin_amdgcn_mfma_f32_32x32x16_bf16(a1[s], bs, acc1, 0, 0, 0);
    }
    const unsigned kinv = (unsigned)(kinvBase - kt * 32);
    #pragma unroll
    for (int r = 0; r < 16; r++){
      // s'' = 4 - ||w||^2 + 2*dot in [1,5]; fixed-point *2^19 (trunc, monotone)
      float s0 = fmaf(2.0f, acc0[r], c4k);
      unsigned u0 = ((unsigned)(s0 * 524288.0f) << 10) | kinv;
      b2k[0][r] = max(b2k[0][r], min(b1k[0][r], u0));
      b1k[0][r] = max(b1k[0][r], u0);
      float s1 = fmaf(2.0f, acc1[r], c4k);
      unsigned u1 = ((unsigned)(s1 * 524288.0f) << 10) | kinv;
      b2k[1][r] = max(b2k[1][r], min(b1k[1][r], u1));
      b1k[1][r] = max(b1k[1][r], u1);
    }
    __syncthreads();
  }
  #pragma unroll
  for (int m = 1; m < 32; m <<= 1){
    #pragma unroll
    for (int ti = 0; ti < 2; ti++){
      #pragma unroll
      for (int r = 0; r < 16; r++){
        unsigned o1 = (unsigned)__shfl_xor((int)b1k[ti][r], m, 64);
        unsigned o2 = (unsigned)__shfl_xor((int)b2k[ti][r], m, 64);
        b2k[ti][r] = max(max(b2k[ti][r], o2), min(b1k[ti][r], o1));
        b1k[ti][r] = max(b1k[ti][r], o1);
      }
    }
  }
  if (col == 0){
    #pragma unroll
    for (int ti = 0; ti < 2; ti++){
      #pragma unroll
      for (int r = 0; r < 16; r++){
        int rowD = (r & 3) + 8 * (r >> 2) + 4 * half;  // verified C/D map [m74/m101]
        int n = rowBase + ti * 32 + rowD;
        pairs[(size_t)n * 2 + hb] = make_uint2(b1k[ti][r], b2k[ti][r]);
      }
    }
  }
}

// ---------------- K2m: merge two code-half top-2s, emit idx + flags (integer gap)
__global__ __launch_bounds__(256) void kern_merge(
    const uint2* __restrict__ pairs, int* __restrict__ idx_i, float* __restrict__ idx_f,
    int* __restrict__ flag_list, unsigned int* __restrict__ flag_count)
{
  const int n = blockIdx.x * 256 + threadIdx.x;
  uint2 p0 = pairs[(size_t)n * 2];
  uint2 p1 = pairs[(size_t)n * 2 + 1];
  unsigned B1 = max(p0.x, p1.x);
  unsigned B2 = max(max(p0.y, p1.y), min(p0.x, p1.x));
  int idx = 1023 - (int)(B1 & 1023u);
  idx_i[n] = idx;
  idx_f[n] = (float)idx;
  bool f = ((B1 >> 10) - (B2 >> 10)) < TFLAG_FIX;
  unsigned long long m = __ballot(f);
  if (m){
    int lane = threadIdx.x & 63;
    int leader = __ffsll((unsigned long long)m) - 1;
    unsigned base = 0;
    if (lane == leader) base = atomicAdd(flag_count, (unsigned)__popcll(m));
    base = (unsigned)__shfl((int)base, leader, 64);
    if (f){
      int off = __popcll(m & ((1ull << lane) - 1ull));
      flag_list[base + off] = n;
    }
  }
}

// ---------------- K2b: exact-fp32 rescore of flagged rows. Per-(row,k) chain is
// BIT-IDENTICAL to the validated rescue: serial fp32 fmaf over c=0..255
// (zf = hi+lo), s = fmaf(-2, dot, wnn[k]), argmin with lowest-index tie-break
// (realized exactly via 64-bit (orderable-float, k) key min-reduce).
// R8: K-SPLIT-2 — each 16-row batch is handled by TWO blocks (hb = codebook
// half; thread owns 2 codes instead of 4). R7 counters: 67us, occ 8.6%
// (cnt/16 ~ 412 blocks = 1.6/CU), VALU 27% -> latency-bound from too few
// resident waves. K-split doubles active blocks at UNCHANGED total codebook
// traffic (each block reads half), halves the serial chain, acc 64->32 VGPR.
// Each half-block writes its per-row min-key to keys[n*2+hb] (aliases the
// dead `pairs` buffer); kern_rescue_fin takes the min of the two halves —
// the exact reduction the single block did internally.
__global__ __launch_bounds__(256) void kern_rescue(
    const uint4* __restrict__ zfh4, const uint4* __restrict__ zfl4,
    const float* __restrict__ wnT, const float* __restrict__ wnn,
    const int* __restrict__ flag_list, const unsigned int* __restrict__ flag_count,
    unsigned long long* __restrict__ keys)
{
  __shared__ float sz[16][256];
  __shared__ unsigned long long sred[4][16];
  __shared__ int srow[16];
  const int t = threadIdx.x;
  const int lane = t & 63, wvi = t >> 6;
  const int cnt = (int)*flag_count;
  const int hb = blockIdx.x & 1;
  const int bb = blockIdx.x >> 1;
  if (bb * 16 >= cnt) return;   // uniform early-out for idle blocks
  const int k0 = hb * 512 + t * 2;
  const float wq0 = wnn[k0+0], wq1 = wnn[k0+1];
  const float2* wt2 = (const float2*)wnT;  // [256][1024] f32 -> float2 idx c*512 + (k>>1)
  const size_t ko2 = (size_t)(k0 >> 1);

  for (int base = bb * 16; base < cnt; base += (gridDim.x >> 1) * 16){
    const int nr = min(16, cnt - base);
    __syncthreads();
    if (t < 16) srow[t] = flag_list[base + min(t, nr - 1)];  // pad: duplicate last row
    __syncthreads();
    #pragma unroll
    for (int j = 0; j < 2; j++){
      int p = t + j * 256;
      int r = p >> 5, q = p & 31;
      int n = srow[r];
      size_t o = (size_t)(n >> 5) * 1024 + (size_t)q * 32 + (n & 31);
      U4S8 h, l; h.v = zfh4[o]; l.v = zfl4[o];
      #pragma unroll
      for (int e = 0; e < 8; e++) sz[r][q*8+e] = bf2f(h.u[e]) + bf2f(l.u[e]);
    }
    __syncthreads();

    float acc[2][16];
    #pragma unroll
    for (int j = 0; j < 2; j++)
      #pragma unroll
      for (int r = 0; r < 16; r++) acc[j][r] = 0.0f;
    for (int c4 = 0; c4 < 64; c4++){
      // coalesced: wave-contiguous 512B of wnT row (channel 4*c4+i), half hb
      float2 cv0 = wt2[(size_t)(4*c4+0)*512 + ko2];
      float2 cv1 = wt2[(size_t)(4*c4+1)*512 + ko2];
      float2 cv2 = wt2[(size_t)(4*c4+2)*512 + ko2];
      float2 cv3 = wt2[(size_t)(4*c4+3)*512 + ko2];
      #pragma unroll
      for (int r = 0; r < 16; r++){
        float4 s = ((const float4*)sz[r])[c4];   // broadcast LDS read
        acc[0][r] = fmaf(s.x, cv0.x, acc[0][r]);
        acc[0][r] = fmaf(s.y, cv1.x, acc[0][r]);
        acc[0][r] = fmaf(s.z, cv2.x, acc[0][r]);
        acc[0][r] = fmaf(s.w, cv3.x, acc[0][r]);
        acc[1][r] = fmaf(s.x, cv0.y, acc[1][r]);
        acc[1][r] = fmaf(s.y, cv1.y, acc[1][r]);
        acc[1][r] = fmaf(s.z, cv2.y, acc[1][r]);
        acc[1][r] = fmaf(s.w, cv3.y, acc[1][r]);
      }
    }
    #pragma unroll
    for (int r = 0; r < 16; r++){
      float s0 = fmaf(-2.0f, acc[0][r], wq0);
      float s1 = fmaf(-2.0f, acc[1][r], wq1);
      float bv = s0; int bi = k0;
      if (s1 < bv){ bv = s1; bi = k0 + 1; }
      unsigned u = __float_as_uint(bv);
      u = (u & 0x80000000u) ? ~u : (u | 0x80000000u);   // orderable float
      unsigned long long key = ((unsigned long long)u << 10) | (unsigned)bi;
      #pragma unroll
      for (int m = 1; m < 64; m <<= 1){
        unsigned long long o = shfl_xor_u64(key, m);
        if (o < key) key = o;
      }
      if (lane == 0) sred[wvi][r] = key;
    }
    __syncthreads();
    if (t < nr){
      unsigned long long ka = sred[0][t] < sred[1][t] ? sred[0][t] : sred[1][t];
      unsigned long long kb = sred[2][t] < sred[3][t] ? sred[2][t] : sred[3][t];
      unsigned long long kf = ka < kb ? ka : kb;
      keys[(size_t)srow[t] * 2 + hb] = kf;
    }
  }
}

// ---------------- K2c: merge the two codebook-half keys -> final idx
__global__ __launch_bounds__(256) void kern_rescue_fin(
    const unsigned long long* __restrict__ keys, const int* __restrict__ flag_list,
    const unsigned int* __restrict__ flag_count,
    int* __restrict__ idx_i, float* __restrict__ idx_f)
{
  const int cnt = (int)*flag_count;
  for (int i = blockIdx.x * 256 + threadIdx.x; i < cnt; i += gridDim.x * 256){
    int n = flag_list[i];
    unsigned long long ka = keys[(size_t)n * 2];
    unsigned long long kb = keys[(size_t)n * 2 + 1];
    unsigned long long kf = ka < kb ? ka : kb;
    int fi = (int)(kf & 1023ull);
    idx_i[n] = fi;
    idx_f[n] = (float)fi;
  }
}

// ---------------- K3: gather z_q = embedding[idx] back to [B,C,H,W] + loss sum
// Direct per-thread z load (no LDS tile): row r=t>>2, w-chunk (t&3)*16..+15 as
// 4 float4s (wave pattern byte-identical). Row norm = 16-fmaf partial + 2
// shfl_xor over the 4-lane group. emb gather float4, transposed via slim zq LDS.
__global__ __launch_bounds__(256) void kern_gather(
    const float* __restrict__ z, const float* __restrict__ emb,
    const int* __restrict__ idx_i, float* __restrict__ out,
    float* __restrict__ loss_acc)
{
  __shared__ float zq[64][65];   // [c_local][w]
  __shared__ int sidx[64];
  __shared__ float swsum[4];
  const int t = threadIdx.x;
  const int ct = blockIdx.x & 3;
  const int bh = blockIdx.x >> 2;
  const int c0 = ct * 64;
  if (t < 64) sidx[t] = idx_i[bh*64 + t];

  // direct per-thread z load: row r = t>>2, w-chunk (t&3)*16 .. +15
  const int r = t >> 2, w0 = (t & 3) * 16;
  const float4* zr = (const float4*)(z + ((size_t)(bh >> 6) * 256 + c0 + r) * 4096
                                       + (size_t)(bh & 63) * 64 + w0);
  float4 tz0 = zr[0], tz1 = zr[1], tz2 = zr[2], tz3 = zr[3];
  __syncthreads();   // sidx ready

  // gather phase: thread covers channels 4*(t&15)..+3, w = (t>>4) + 16*it
  {
    const int ch4 = (t & 15) * 4, wrow = t >> 4;
    #pragma unroll
    for (int it = 0; it < 4; it++){
      int w = wrow + 16*it;
      float4 qv = *(const float4*)(emb + (size_t)sidx[w] * 256 + c0 + ch4);
      zq[ch4+0][w] = qv.x; zq[ch4+1][w] = qv.y;
      zq[ch4+2][w] = qv.z; zq[ch4+3][w] = qv.w;
    }
  }
  // row norm: own 16-elem partial + reduce across the 4-lane row group
  float ss = 0.f;
  ss = fmaf(tz0.x, tz0.x, ss); ss = fmaf(tz0.y, tz0.y, ss);
  ss = fmaf(tz0.z, tz0.z, ss); ss = fmaf(tz0.w, tz0.w, ss);
  ss = fmaf(tz1.x, tz1.x, ss); ss = fmaf(tz1.y, tz1.y, ss);
  ss = fmaf(tz1.z, tz1.z, ss); ss = fmaf(tz1.w, tz1.w, ss);
  ss = fmaf(tz2.x, tz2.x, ss); ss = fmaf(tz2.y, tz2.y, ss);
  ss = fmaf(tz2.z, tz2.z, ss); ss = fmaf(tz2.w, tz2.w, ss);
  ss = fmaf(tz3.x, tz3.x, ss); ss = fmaf(tz3.y, tz3.y, ss);
  ss = fmaf(tz3.z, tz3.z, ss); ss = fmaf(tz3.w, tz3.w, ss);
  ss += __shfl_xor(ss, 1, 64);
  ss += __shfl_xor(ss, 2, 64);
  const float inv = 1.0f / fmaxf(sqrtf(ss), 1e-12f);
  __syncthreads();   // zq ready

  float lsum = 0.f;
  float* op = out + ((size_t)(bh >> 6) * 256 + c0 + r) * 4096
                  + (size_t)(bh & 63) * 64 + w0;
  #pragma unroll
  for (int i = 0; i < 4; i++){
    float4 tzv = (i == 0) ? tz0 : (i == 1) ? tz1 : (i == 2) ? tz2 : tz3;
    int w = w0 + 4*i;
    float q0 = zq[r][w+0], q1 = zq[r][w+1], q2 = zq[r][w+2], q3 = zq[r][w+3];
    float d0 = q0 - tzv.x * inv;
    float d1 = q1 - tzv.y * inv;
    float d2 = q2 - tzv.z * inv;
    float d3 = q3 - tzv.w * inv;
    lsum = fmaf(d0, d0, lsum); lsum = fmaf(d1, d1, lsum);
    lsum = fmaf(d2, d2, lsum); lsum = fmaf(d3, d3, lsum);
    ((float4*)op)[i] = make_float4(q0, q1, q2, q3);
  }
  #pragma unroll
  for (int m = 32; m > 0; m >>= 1) lsum += __shfl_down(lsum, m, 64);
  if ((t & 63) == 0) swsum[t >> 6] = lsum;
  __syncthreads();
  if (t == 0) atomicAdd(loss_acc, swsum[0] + swsum[1] + swsum[2] + swsum[3]);
}

// ---------------- K4: finalize loss = (1 + BETA) * mean
__global__ void kern_final(const float* __restrict__ loss_acc, float* __restrict__ out_loss){
  if (threadIdx.x == 0 && blockIdx.x == 0)
    out_loss[0] = 1.25f * loss_acc[0] * (1.0f / 16777216.0f);
}

extern "C" void kernel_launch(void* const* d_in, const int* in_sizes, int n_in,
                              void* d_out, int out_size, void* d_ws, size_t ws_size,
                              hipStream_t stream)
{
  const float* z   = (const float*)d_in[0];
  const float* emb = (const float*)d_in[1];
  char* ws = (char*)d_ws;
  unsigned int* flag_count = (unsigned int*)(ws + 0);
  float* loss_acc          = (float*)(ws + 8);
  float* wnn               = (float*)(ws + 1024);
  float* wnn4              = (float*)(ws + 8192);
  float* wnT               = (float*)(ws + 16384);   // transposed codebook [256][1024] f32
  uint4* wnh4              = (uint4*)(ws + 1064960);
  int* idx_i               = (int*)(ws + 1589248);
  int* flag_list           = (int*)(ws + 1851392);
  uint2* pairs             = (uint2*)(ws + 2113536);
  // keys aliases pairs: pairs is dead after kern_merge; 16B/row both ways.
  unsigned long long* keys = (unsigned long long*)(ws + 2113536);
  uint4* zfh4              = (uint4*)(ws + 3162112);
  uint4* zfl4              = (uint4*)(ws + 36716544);
  float* out_zq   = (float*)d_out;
  float* out_idx  = (float*)d_out + 16777216;
  float* out_loss = (float*)d_out + 16842752;

  hipMemsetAsync(ws, 0, 16, stream);  // flag_count + loss accumulator
  kern_prep<<<KK, 64, 0, stream>>>(emb, wnT, wnh4, wnn, wnn4);
  kern_znorm<<<4096, 256, 0, stream>>>(z, zfh4, zfl4);
  kern_gemm<<<512, 256, 0, stream>>>(zfh4, wnh4, wnn4, pairs);
  kern_merge<<<256, 256, 0, stream>>>(pairs, idx_i, out_idx, flag_list, flag_count);
  kern_rescue<<<1024, 256, 0, stream>>>(zfh4, zfl4, wnT, wnn, flag_list, flag_count,
                                        keys);
  kern_rescue_fin<<<64, 256, 0, stream>>>(keys, flag_list, flag_count, idx_i, out_idx);
  kern_gather<<<4096, 256, 0, stream>>>(z, emb, idx_i, out_zq, loss_acc);
  kern_final<<<1, 64, 0, stream>>>(loss_acc, out_loss);
}

// Round 5
// 272.328 us; speedup vs baseline: 1.0973x; 1.0973x over previous
//
#include <hip/hip_runtime.h>

// Problem constants (z: [16,256,64,64] f32, embedding: [1024,256] f32)
#define NN 65536   // B*H*W rows
#define KK 1024
// flag if fixed-point top-2 gap < 2098 (= 4e-3 * 2^19): ~10 sigma of 1-pass bf16 noise
#define TFLAG_FIX 2098u

typedef __bf16 bf16x8 __attribute__((ext_vector_type(8)));
typedef float f32x16 __attribute__((ext_vector_type(16)));

__device__ __forceinline__ unsigned short f2bf(float x){
  unsigned u = __float_as_uint(x);
  u += 0x7FFFu + ((u >> 16) & 1u);
  return (unsigned short)(u >> 16);
}
__device__ __forceinline__ float bf2f(unsigned short h){
  return __uint_as_float(((unsigned)h) << 16);
}
__device__ __forceinline__ void dma16(const uint4* g, uint4* l){
  __builtin_amdgcn_global_load_lds(
      (const __attribute__((address_space(1))) void*)g,
      (__attribute__((address_space(3))) void*)l, 16, 0, 0);
}
__device__ __forceinline__ unsigned long long shfl_xor_u64(unsigned long long v, int m){
  unsigned lo = (unsigned)__shfl_xor((int)(unsigned)v, m, 64);
  unsigned hi = (unsigned)__shfl_xor((int)(unsigned)(v >> 32), m, 64);
  return ((unsigned long long)hi << 32) | lo;
}
union U4S8 { uint4 v; unsigned short u[8]; };

// Fragment-major layout for bf16 matrices [rows][256 c]:
// uint4 (8 c-elems) for (row n, chunk q=c>>3) at index (n>>5)*1024 + q*32 + (n&31).

// ---------------- K0: normalize codebook. wnT is stored TRANSPOSED [c][k] (f32)
// so the rescue role's per-channel codebook read is wave-coalesced.
__global__ __launch_bounds__(64) void kern_prep(const float* __restrict__ emb,
    float* __restrict__ wnT, uint4* __restrict__ wnh4,
    float* __restrict__ wnn, float* __restrict__ wnn4)
{
  const int k = blockIdx.x, t = threadIdx.x;
  float4 v = ((const float4*)emb)[k*64 + t];
  float ss = fmaf(v.x, v.x, fmaf(v.y, v.y, fmaf(v.z, v.z, v.w * v.w)));
  #pragma unroll
  for (int m = 32; m > 0; m >>= 1) ss += __shfl_xor(ss, m, 64);
  float d = fmaxf(sqrtf(ss), 1e-12f);
  float w0 = v.x / d, w1 = v.y / d, w2 = v.z / d, w3 = v.w / d;
  // transposed store: wnT[c][k], c = 4t..4t+3 (one-time scattered 1MB write)
  wnT[(size_t)(4*t+0)*1024 + k] = w0;
  wnT[(size_t)(4*t+1)*1024 + k] = w1;
  wnT[(size_t)(4*t+2)*1024 + k] = w2;
  wnT[(size_t)(4*t+3)*1024 + k] = w3;
  unsigned short* base = (unsigned short*)wnh4;
  size_t o = ((size_t)(k >> 5) * 1024 + (size_t)(t >> 1) * 32 + (k & 31)) * 8 + (t & 1) * 4;
  base[o+0] = f2bf(w0); base[o+1] = f2bf(w1); base[o+2] = f2bf(w2); base[o+3] = f2bf(w3);
  float s2 = fmaf(w0, w0, fmaf(w1, w1, fmaf(w2, w2, w3 * w3)));
  #pragma unroll
  for (int m = 32; m > 0; m >>= 1) s2 += __shfl_xor(s2, m, 64);
  if (t == 0){ wnn[k] = s2; wnn4[k] = 4.0f - s2; }
}

// ---------------- K1: L2-normalize z along W, transpose to [N,C], split bf16 hi/lo,
// store BOTH in fragment-major layout. grid: (b*64+h)*4 + c-tile; block 256.
__global__ __launch_bounds__(256) void kern_znorm(const float* __restrict__ z,
    uint4* __restrict__ zfh4, uint4* __restrict__ zfl4)
{
  __shared__ float tile[64][65];  // [c_local][w]
  __shared__ float sinv[64];
  const int t = threadIdx.x;
  const int ct = blockIdx.x & 3;
  const int bh = blockIdx.x >> 2;     // b*64 + h
  const int c0 = ct * 64, q0 = ct * 8;
  const int cl = t >> 2, q = t & 3;
  const float4* zr = (const float4*)(z + ((size_t)(bh >> 6) * 256 + c0 + cl) * 4096
                                       + (size_t)(bh & 63) * 64);
  #pragma unroll
  for (int i = 0; i < 4; i++){
    float4 v = zr[q + 4*i];
    int w = (q + 4*i) * 4;
    tile[cl][w] = v.x; tile[cl][w+1] = v.y; tile[cl][w+2] = v.z; tile[cl][w+3] = v.w;
  }
  __syncthreads();
  if (t < 64){
    float ss = 0.f;
    #pragma unroll
    for (int w = 0; w < 64; w++){ float x = tile[t][w]; ss = fmaf(x, x, ss); }
    sinv[t] = 1.0f / fmaxf(sqrtf(ss), 1e-12f);
  }
  __syncthreads();
  #pragma unroll
  for (int j = 0; j < 2; j++){
    int p = t + 256 * j;
    int tI = p >> 8, rem = p & 255;
    int qq = rem >> 5, colI = rem & 31;
    int w = tI * 32 + colI;
    U4S8 hh, ll;
    #pragma unroll
    for (int e = 0; e < 8; e++){
      int c = qq * 8 + e;
      float v = tile[c][w] * sinv[c];
      hh.u[e] = f2bf(v);
      ll.u[e] = f2bf(v - bf2f(hh.u[e]));
    }
    size_t o = (size_t)(bh * 2 + tI) * 1024 + (size_t)(q0 + qq) * 32 + colI;
    zfh4[o] = hh.v;
    zfl4[o] = ll.v;
  }
}

// ---------------- K2: 1-pass bf16 MFMA GEMM, 64 rows x 32 codes per wave,
// code-split-2, DMA-staged double-buffered B, fixed-point packed-key top-2 per row.
__global__ __launch_bounds__(256, 2) void kern_gemm(
    const uint4* __restrict__ zA, const uint4* __restrict__ wB,
    const float* __restrict__ wnn4, uint2* __restrict__ pairs)
{
  __shared__ uint4 sB[2][1024];
  const int t = threadIdx.x;
  const int wv = t >> 6;
  const int lane = t & 63;
  const int col = lane & 31;
  const int half = lane >> 5;
  const int hb = blockIdx.x & 1;
  const int cb = hb * 512;
  const int rowBase = (blockIdx.x >> 1) * 256 + wv * 64;
  const int T0 = rowBase >> 5;

  bf16x8 a0[16], a1[16];
  {
    const uint4* r0 = zA + (size_t)T0 * 1024;
    const uint4* r1 = zA + (size_t)(T0 + 1) * 1024;
    const uint4* g0 = wB + (size_t)(cb >> 5) * 1024;
    dma16(g0 + (wv*4+0)*64 + lane, &sB[0][(wv*4+0)*64 + lane]);
    dma16(g0 + (wv*4+1)*64 + lane, &sB[0][(wv*4+1)*64 + lane]);
    dma16(g0 + (wv*4+2)*64 + lane, &sB[0][(wv*4+2)*64 + lane]);
    dma16(g0 + (wv*4+3)*64 + lane, &sB[0][(wv*4+3)*64 + lane]);
    #pragma unroll
    for (int s = 0; s < 16; s++){
      a0[s] = __builtin_bit_cast(bf16x8, r0[(2*s + half)*32 + col]);
      a1[s] = __builtin_bit_cast(bf16x8, r1[(2*s + half)*32 + col]);
    }
  }
  unsigned b1k[2][16], b2k[2][16];
  #pragma unroll
  for (int r = 0; r < 16; r++){
    b1k[0][r] = 0u; b1k[1][r] = 0u; b2k[0][r] = 0u; b2k[1][r] = 0u;
  }
  const int kinvBase = 1023 - cb - col;
  __syncthreads();

  for (int kt = 0; kt < 16; kt++){
    if (kt < 15){
      const uint4* gn = wB + (size_t)((cb >> 5) + kt + 1) * 1024;
      uint4* ld = &sB[(kt + 1) & 1][0];
      dma16(gn + (wv*4+0)*64 + lane, ld + (wv*4+0)*64 + lane);
      dma16(gn + (wv*4+1)*64 + lane, ld + (wv*4+1)*64 + lane);
      dma16(gn + (wv*4+2)*64 + lane, ld + (wv*4+2)*64 + lane);
      dma16(gn + (wv*4+3)*64 + lane, ld + (wv*4+3)*64 + lane);
    }
    const float c4k = wnn4[cb + kt*32 + col];
    const uint4* bp = &sB[kt & 1][half * 32 + col];
    f32x16 acc0, acc1;
    #pragma unroll
    for (int i = 0; i < 16; i++){ acc0[i] = 0.0f; acc1[i] = 0.0f; }
    #pragma unroll
    for (int s = 0; s < 16; s++){
      bf16x8 bs = __builtin_bit_cast(bf16x8, bp[s * 64]);
      acc0 = __builtin_amdgcn_mfma_f32_32x32x16_bf16(a0[s], bs, acc0, 0, 0, 0);
      acc1 = __builtin_amdgcn_mfma_f32_32x32x16_bf16(a1[s], bs, acc1, 0, 0, 0);
    }
    const unsigned kinv = (unsigned)(kinvBase - kt * 32);
    #pragma unroll
    for (int r = 0; r < 16; r++){
      // s'' = 4 - ||w||^2 + 2*dot in [1,5]; fixed-point *2^19 (trunc, monotone)
      float s0 = fmaf(2.0f, acc0[r], c4k);
      unsigned u0 = ((unsigned)(s0 * 524288.0f) << 10) | kinv;
      b2k[0][r] = max(b2k[0][r], min(b1k[0][r], u0));
      b1k[0][r] = max(b1k[0][r], u0);
      float s1 = fmaf(2.0f, acc1[r], c4k);
      unsigned u1 = ((unsigned)(s1 * 524288.0f) << 10) | kinv;
      b2k[1][r] = max(b2k[1][r], min(b1k[1][r], u1));
      b1k[1][r] = max(b1k[1][r], u1);
    }
    __syncthreads();
  }
  #pragma unroll
  for (int m = 1; m < 32; m <<= 1){
    #pragma unroll
    for (int ti = 0; ti < 2; ti++){
      #pragma unroll
      for (int r = 0; r < 16; r++){
        unsigned o1 = (unsigned)__shfl_xor((int)b1k[ti][r], m, 64);
        unsigned o2 = (unsigned)__shfl_xor((int)b2k[ti][r], m, 64);
        b2k[ti][r] = max(max(b2k[ti][r], o2), min(b1k[ti][r], o1));
        b1k[ti][r] = max(b1k[ti][r], o1);
      }
    }
  }
  if (col == 0){
    #pragma unroll
    for (int ti = 0; ti < 2; ti++){
      #pragma unroll
      for (int r = 0; r < 16; r++){
        int rowD = (r & 3) + 8 * (r >> 2) + 4 * half;  // verified C/D map [m74/m101]
        int n = rowBase + ti * 32 + rowD;
        pairs[(size_t)n * 2 + hb] = make_uint2(b1k[ti][r], b2k[ti][r]);
      }
    }
  }
}

// ---------------- K2m: merge two code-half top-2s, emit idx + flags (integer gap)
__global__ __launch_bounds__(256) void kern_merge(
    const uint2* __restrict__ pairs, int* __restrict__ idx_i, float* __restrict__ idx_f,
    int* __restrict__ flag_list, unsigned int* __restrict__ flag_count)
{
  const int n = blockIdx.x * 256 + threadIdx.x;
  uint2 p0 = pairs[(size_t)n * 2];
  uint2 p1 = pairs[(size_t)n * 2 + 1];
  unsigned B1 = max(p0.x, p1.x);
  unsigned B2 = max(max(p0.y, p1.y), min(p0.x, p1.x));
  int idx = 1023 - (int)(B1 & 1023u);
  idx_i[n] = idx;
  idx_f[n] = (float)idx;
  bool f = ((B1 >> 10) - (B2 >> 10)) < TFLAG_FIX;
  unsigned long long m = __ballot(f);
  if (m){
    int lane = threadIdx.x & 63;
    int leader = __ffsll((unsigned long long)m) - 1;
    unsigned base = 0;
    if (lane == leader) base = atomicAdd(flag_count, (unsigned)__popcll(m));
    base = (unsigned)__shfl((int)base, leader, 64);
    if (f){
      int off = __popcll(m & ((1ull << lane) - 1ull));
      flag_list[base + off] = n;
    }
  }
}

// ---------------- FUSED rescue + gather.
// R9: rescue (69us, latency-bound, 4.6% HBM) and gather (62us, latency-bound,
// 21% HBM) ran back-to-back, each leaving most of the machine idle. They have
// no true dependency: gather needs final idx only for the ~10% flagged rows.
// Fuse: blocks 0..1023 = rescue role (R4 K-split-2 body, BIT-IDENTICAL fp32
// chain, writes `keys` ONLY — idx_i untouched, no race); blocks 1024..5119 =
// gather role using merge's provisional idx. Rescue dispatches first (long
// pole); gather's 4096 blocks backfill idle wave slots and the two workloads
// hide each other's latency. kern_patch afterwards fixes the flagged rows
// whose final idx changed (out row rewrite + loss delta).
struct RescueSM {
  float sz[16][256];
  unsigned long long sred[4][16];
  int srow[16];
};
struct GatherSM {
  float zq[64][65];
  int sidx[64];
  float swsum[4];
};

__global__ __launch_bounds__(256) void kern_fused(
    const float* __restrict__ z, const float* __restrict__ emb,
    const int* __restrict__ idx_i, float* __restrict__ out,
    float* __restrict__ loss_acc,
    const uint4* __restrict__ zfh4, const uint4* __restrict__ zfl4,
    const float* __restrict__ wnT, const float* __restrict__ wnn,
    const int* __restrict__ flag_list, const unsigned int* __restrict__ flag_count,
    unsigned long long* __restrict__ keys)
{
  __shared__ union { RescueSM r; GatherSM g; } sm;
  const int t = threadIdx.x;

  if (blockIdx.x < 1024){
    // ---------- rescue role (exact-fp32 rescore, K-split-2, 16 rows/batch) ----------
    const int lane = t & 63, wvi = t >> 6;
    const int cnt = (int)*flag_count;
    const int hb = blockIdx.x & 1;
    const int bb = blockIdx.x >> 1;
    if (bb * 16 >= cnt) return;   // uniform early-out for idle blocks
    const int k0 = hb * 512 + t * 2;
    const float wq0 = wnn[k0+0], wq1 = wnn[k0+1];
    const float2* wt2 = (const float2*)wnT;  // [256][1024] -> float2 idx c*512 + (k>>1)
    const size_t ko2 = (size_t)(k0 >> 1);

    for (int base = bb * 16; base < cnt; base += 512 * 16){
      const int nr = min(16, cnt - base);
      __syncthreads();
      if (t < 16) sm.r.srow[t] = flag_list[base + min(t, nr - 1)];  // pad: dup last
      __syncthreads();
      #pragma unroll
      for (int j = 0; j < 2; j++){
        int p = t + j * 256;
        int r = p >> 5, q = p & 31;
        int n = sm.r.srow[r];
        size_t o = (size_t)(n >> 5) * 1024 + (size_t)q * 32 + (n & 31);
        U4S8 h, l; h.v = zfh4[o]; l.v = zfl4[o];
        #pragma unroll
        for (int e = 0; e < 8; e++) sm.r.sz[r][q*8+e] = bf2f(h.u[e]) + bf2f(l.u[e]);
      }
      __syncthreads();

      float acc[2][16];
      #pragma unroll
      for (int j = 0; j < 2; j++)
        #pragma unroll
        for (int r = 0; r < 16; r++) acc[j][r] = 0.0f;
      for (int c4 = 0; c4 < 64; c4++){
        float2 cv0 = wt2[(size_t)(4*c4+0)*512 + ko2];
        float2 cv1 = wt2[(size_t)(4*c4+1)*512 + ko2];
        float2 cv2 = wt2[(size_t)(4*c4+2)*512 + ko2];
        float2 cv3 = wt2[(size_t)(4*c4+3)*512 + ko2];
        #pragma unroll
        for (int r = 0; r < 16; r++){
          float4 s = ((const float4*)sm.r.sz[r])[c4];   // broadcast LDS read
          acc[0][r] = fmaf(s.x, cv0.x, acc[0][r]);
          acc[0][r] = fmaf(s.y, cv1.x, acc[0][r]);
          acc[0][r] = fmaf(s.z, cv2.x, acc[0][r]);
          acc[0][r] = fmaf(s.w, cv3.x, acc[0][r]);
          acc[1][r] = fmaf(s.x, cv0.y, acc[1][r]);
          acc[1][r] = fmaf(s.y, cv1.y, acc[1][r]);
          acc[1][r] = fmaf(s.z, cv2.y, acc[1][r]);
          acc[1][r] = fmaf(s.w, cv3.y, acc[1][r]);
        }
      }
      #pragma unroll
      for (int r = 0; r < 16; r++){
        float s0 = fmaf(-2.0f, acc[0][r], wq0);
        float s1 = fmaf(-2.0f, acc[1][r], wq1);
        float bv = s0; int bi = k0;
        if (s1 < bv){ bv = s1; bi = k0 + 1; }
        unsigned u = __float_as_uint(bv);
        u = (u & 0x80000000u) ? ~u : (u | 0x80000000u);   // orderable float
        unsigned long long key = ((unsigned long long)u << 10) | (unsigned)bi;
        #pragma unroll
        for (int m = 1; m < 64; m <<= 1){
          unsigned long long o = shfl_xor_u64(key, m);
          if (o < key) key = o;
        }
        if (lane == 0) sm.r.sred[wvi][r] = key;
      }
      __syncthreads();
      if (t < nr){
        unsigned long long ka = sm.r.sred[0][t] < sm.r.sred[1][t] ? sm.r.sred[0][t] : sm.r.sred[1][t];
        unsigned long long kb = sm.r.sred[2][t] < sm.r.sred[3][t] ? sm.r.sred[2][t] : sm.r.sred[3][t];
        unsigned long long kf = ka < kb ? ka : kb;
        keys[(size_t)sm.r.srow[t] * 2 + hb] = kf;
      }
    }
    return;
  }

  // ---------- gather role: z_q = emb[idx_prov] back to [B,C,H,W] + loss sum ----------
  const int gb = blockIdx.x - 1024;
  const int ct = gb & 3;
  const int bh = gb >> 2;
  const int c0 = ct * 64;
  if (t < 64) sm.g.sidx[t] = idx_i[bh*64 + t];

  // direct per-thread z load: row r = t>>2, w-chunk (t&3)*16 .. +15
  const int r = t >> 2, w0 = (t & 3) * 16;
  const float4* zr = (const float4*)(z + ((size_t)(bh >> 6) * 256 + c0 + r) * 4096
                                       + (size_t)(bh & 63) * 64 + w0);
  float4 tz0 = zr[0], tz1 = zr[1], tz2 = zr[2], tz3 = zr[3];
  __syncthreads();   // sidx ready

  {
    const int ch4 = (t & 15) * 4, wrow = t >> 4;
    #pragma unroll
    for (int it = 0; it < 4; it++){
      int w = wrow + 16*it;
      float4 qv = *(const float4*)(emb + (size_t)sm.g.sidx[w] * 256 + c0 + ch4);
      sm.g.zq[ch4+0][w] = qv.x; sm.g.zq[ch4+1][w] = qv.y;
      sm.g.zq[ch4+2][w] = qv.z; sm.g.zq[ch4+3][w] = qv.w;
    }
  }
  float ss = 0.f;
  ss = fmaf(tz0.x, tz0.x, ss); ss = fmaf(tz0.y, tz0.y, ss);
  ss = fmaf(tz0.z, tz0.z, ss); ss = fmaf(tz0.w, tz0.w, ss);
  ss = fmaf(tz1.x, tz1.x, ss); ss = fmaf(tz1.y, tz1.y, ss);
  ss = fmaf(tz1.z, tz1.z, ss); ss = fmaf(tz1.w, tz1.w, ss);
  ss = fmaf(tz2.x, tz2.x, ss); ss = fmaf(tz2.y, tz2.y, ss);
  ss = fmaf(tz2.z, tz2.z, ss); ss = fmaf(tz2.w, tz2.w, ss);
  ss = fmaf(tz3.x, tz3.x, ss); ss = fmaf(tz3.y, tz3.y, ss);
  ss = fmaf(tz3.z, tz3.z, ss); ss = fmaf(tz3.w, tz3.w, ss);
  ss += __shfl_xor(ss, 1, 64);
  ss += __shfl_xor(ss, 2, 64);
  const float inv = 1.0f / fmaxf(sqrtf(ss), 1e-12f);
  __syncthreads();   // zq ready

  float lsum = 0.f;
  float* op = out + ((size_t)(bh >> 6) * 256 + c0 + r) * 4096
                  + (size_t)(bh & 63) * 64 + w0;
  #pragma unroll
  for (int i = 0; i < 4; i++){
    float4 tzv = (i == 0) ? tz0 : (i == 1) ? tz1 : (i == 2) ? tz2 : tz3;
    int w = w0 + 4*i;
    float q0 = sm.g.zq[r][w+0], q1 = sm.g.zq[r][w+1];
    float q2 = sm.g.zq[r][w+2], q3 = sm.g.zq[r][w+3];
    float d0 = q0 - tzv.x * inv;
    float d1 = q1 - tzv.y * inv;
    float d2 = q2 - tzv.z * inv;
    float d3 = q3 - tzv.w * inv;
    lsum = fmaf(d0, d0, lsum); lsum = fmaf(d1, d1, lsum);
    lsum = fmaf(d2, d2, lsum); lsum = fmaf(d3, d3, lsum);
    ((float4*)op)[i] = make_float4(q0, q1, q2, q3);
  }
  #pragma unroll
  for (int m = 32; m > 0; m >>= 1) lsum += __shfl_down(lsum, m, 64);
  if ((t & 63) == 0) sm.g.swsum[t >> 6] = lsum;
  __syncthreads();
  if (t == 0) atomicAdd(loss_acc, sm.g.swsum[0] + sm.g.swsum[1] + sm.g.swsum[2] + sm.g.swsum[3]);
}

// ---------------- PATCH: for flagged rows, merge half-keys -> final idx; if it
// differs from the provisional, rewrite out_idx + the z_q row and add the loss
// delta. zp reconstructed as hi+lo (== value rescue scored; |zp'-zp| <= 2^-18
// rel -> loss perturbation ~1e-10, negligible). One wave per row.
__global__ __launch_bounds__(256) void kern_patch(
    const uint4* __restrict__ zfh4, const uint4* __restrict__ zfl4,
    const float* __restrict__ emb, const unsigned long long* __restrict__ keys,
    const int* __restrict__ flag_list, const unsigned int* __restrict__ flag_count,
    const int* __restrict__ idx_i, float* __restrict__ out_idx,
    float* __restrict__ out, float* __restrict__ loss_acc)
{
  const int cnt = (int)*flag_count;
  const int wvi = threadIdx.x >> 6, lane = threadIdx.x & 63;
  float dsum = 0.f;
  for (int i = blockIdx.x * 4 + wvi; i < cnt; i += gridDim.x * 4){
    const int n = flag_list[i];
    unsigned long long ka = keys[(size_t)n * 2];
    unsigned long long kb = keys[(size_t)n * 2 + 1];
    unsigned long long kf = ka < kb ? ka : kb;
    const int fi = (int)(kf & 1023ull);
    const int old = idx_i[n];
    if (fi == old) continue;               // wave-uniform
    if (lane == 0) out_idx[n] = (float)fi;
    if (lane < 32){
      size_t o = (size_t)(n >> 5) * 1024 + (size_t)lane * 32 + (n & 31);
      U4S8 h, l; h.v = zfh4[o]; l.v = zfl4[o];
      const float4* eo4 = (const float4*)(emb + (size_t)old * 256 + lane * 8);
      const float4* en4 = (const float4*)(emb + (size_t)fi  * 256 + lane * 8);
      float4 eo0 = eo4[0], eo1 = eo4[1];
      float4 en0 = en4[0], en1 = en4[1];
      float zp[8];
      #pragma unroll
      for (int e = 0; e < 8; e++) zp[e] = bf2f(h.u[e]) + bf2f(l.u[e]);
      float dn, do_;
      dn = en0.x - zp[0]; do_ = eo0.x - zp[0]; dsum += dn*dn - do_*do_;
      dn = en0.y - zp[1]; do_ = eo0.y - zp[1]; dsum += dn*dn - do_*do_;
      dn = en0.z - zp[2]; do_ = eo0.z - zp[2]; dsum += dn*dn - do_*do_;
      dn = en0.w - zp[3]; do_ = eo0.w - zp[3]; dsum += dn*dn - do_*do_;
      dn = en1.x - zp[4]; do_ = eo1.x - zp[4]; dsum += dn*dn - do_*do_;
      dn = en1.y - zp[5]; do_ = eo1.y - zp[5]; dsum += dn*dn - do_*do_;
      dn = en1.z - zp[6]; do_ = eo1.z - zp[6]; dsum += dn*dn - do_*do_;
      dn = en1.w - zp[7]; do_ = eo1.w - zp[7]; dsum += dn*dn - do_*do_;
      // rewrite z_q row: out[b, c, h, w], c = lane*8+e; n = b*4096 + (h*64+w)
      float* ob = out + ((size_t)(n >> 12) * 256 + lane * 8) * 4096 + (n & 4095);
      ob[0*4096] = en0.x; ob[1*4096] = en0.y; ob[2*4096] = en0.z; ob[3*4096] = en0.w;
      ob[4*4096] = en1.x; ob[5*4096] = en1.y; ob[6*4096] = en1.z; ob[7*4096] = en1.w;
    }
  }
  #pragma unroll
  for (int m = 1; m < 32; m <<= 1) dsum += __shfl_xor(dsum, m, 64);
  if (lane == 0 && dsum != 0.f) atomicAdd(loss_acc, dsum);
}

// ---------------- K4: finalize loss = (1 + BETA) * mean
__global__ void kern_final(const float* __restrict__ loss_acc, float* __restrict__ out_loss){
  if (threadIdx.x == 0 && blockIdx.x == 0)
    out_loss[0] = 1.25f * loss_acc[0] * (1.0f / 16777216.0f);
}

extern "C" void kernel_launch(void* const* d_in, const int* in_sizes, int n_in,
                              void* d_out, int out_size, void* d_ws, size_t ws_size,
                              hipStream_t stream)
{
  const float* z   = (const float*)d_in[0];
  const float* emb = (const float*)d_in[1];
  char* ws = (char*)d_ws;
  unsigned int* flag_count = (unsigned int*)(ws + 0);
  float* loss_acc          = (float*)(ws + 8);
  float* wnn               = (float*)(ws + 1024);
  float* wnn4              = (float*)(ws + 8192);
  float* wnT               = (float*)(ws + 16384);   // transposed codebook [256][1024] f32
  uint4* wnh4              = (uint4*)(ws + 1064960);
  int* idx_i               = (int*)(ws + 1589248);
  int* flag_list           = (int*)(ws + 1851392);
  uint2* pairs             = (uint2*)(ws + 2113536);
  // keys aliases pairs: pairs is dead after kern_merge; 16B/row both ways.
  unsigned long long* keys = (unsigned long long*)(ws + 2113536);
  uint4* zfh4              = (uint4*)(ws + 3162112);
  uint4* zfl4              = (uint4*)(ws + 36716544);
  float* out_zq   = (float*)d_out;
  float* out_idx  = (float*)d_out + 16777216;
  float* out_loss = (float*)d_out + 16842752;

  hipMemsetAsync(ws, 0, 16, stream);  // flag_count + loss accumulator
  kern_prep<<<KK, 64, 0, stream>>>(emb, wnT, wnh4, wnn, wnn4);
  kern_znorm<<<4096, 256, 0, stream>>>(z, zfh4, zfl4);
  kern_gemm<<<512, 256, 0, stream>>>(zfh4, wnh4, wnn4, pairs);
  kern_merge<<<256, 256, 0, stream>>>(pairs, idx_i, out_idx, flag_list, flag_count);
  kern_fused<<<5120, 256, 0, stream>>>(z, emb, idx_i, out_zq, loss_acc,
                                       zfh4, zfl4, wnT, wnn, flag_list, flag_count,
                                       keys);
  kern_patch<<<128, 256, 0, stream>>>(zfh4, zfl4, emb, keys, flag_list, flag_count,
                                      idx_i, out_idx, out_zq, loss_acc);
  kern_final<<<1, 64, 0, stream>>>(loss_acc, out_loss);
}